// Round 8
// baseline (129.097 us; speedup 1.0000x reference)
//
#include <hip/hip_runtime.h>

#define NCELLS (16384 * 7 * 7)   // 802816
#define NBLK (NCELLS / 256)      // 3136 blocks, 1 cell/thread (R5's proven bulk)
#define INV_BATCH (1.0f / 16384.0f)
#define EPS 1e-12f
#define IMG 448.0f
#define CELL (448.0f / 7.0f)     // 64
#define L_COORD 5.0f
#define L_NOOBJ 0.5f

__device__ __forceinline__ float iou_f(const float* bp, const float* bt) {
    float cxp = bp[0] * CELL, cyp = bp[1] * CELL;
    float wp  = bp[2] * IMG,  hp  = bp[3] * IMG;
    float cxt = bt[0] * CELL, cyt = bt[1] * CELL;
    float wt  = bt[2] * IMG,  ht  = bt[3] * IMG;
    float iw = fmaxf(fminf(cxp + wp * 0.5f, cxt + wt * 0.5f) -
                     fmaxf(cxp - wp * 0.5f, cxt - wt * 0.5f), 0.0f);
    float ih = fmaxf(fminf(cyp + hp * 0.5f, cyt + ht * 0.5f) -
                     fmaxf(cyp - hp * 0.5f, cyt - ht * 0.5f), 0.0f);
    float inter = iw * ih;
    float uni = wp * hp + wt * ht - inter;
    return inter / (uni + EPS);
}

__device__ __forceinline__ float coord_loss(const float* bp, const float* tb) {
    float xy = (bp[0] - tb[0]) * (bp[0] - tb[0]) + (bp[1] - tb[1]) * (bp[1] - tb[1]);
    float s2 = sqrtf(bp[2] + EPS) - sqrtf(tb[2] + EPS);
    float s3 = sqrtf(bp[3] + EPS) - sqrtf(tb[3] + EPS);
    return xy + s2 * s2 + s3 * s3;
}

// Single kernel: R5's bulk (3136 blocks, 1 cell/thread, direct loads) +
// last-block-done tail instead of a second dispatch.
__global__ void __launch_bounds__(256) yolo_loss_kernel(
        const float* __restrict__ y_pre,
        const float* __restrict__ y_true,
        float* __restrict__ partial,
        unsigned int* __restrict__ counter,
        float* __restrict__ out) {
    const int tid = threadIdx.x;
    const int lane = tid & 63;
    const int wid = tid >> 6;
    const int idx = blockIdx.x * 256 + tid;

    // ---- y_pre: 30 floats, 15x float2 (proven equal to staged loads) ----
    float pv[30];
    const float2* p2 = reinterpret_cast<const float2*>(y_pre + (size_t)idx * 30);
    #pragma unroll
    for (int i = 0; i < 15; ++i) {
        float2 v = p2[i];
        pv[2 * i]     = v.x;
        pv[2 * i + 1] = v.y;
    }
    // ---- y_true: 8 floats, 2x float4 ----
    float tv[8];
    const float4* t4 = reinterpret_cast<const float4*>(y_true) + (size_t)idx * 2;
    float4 ta = t4[0], tb4 = t4[1];
    tv[0] = ta.x; tv[1] = ta.y; tv[2] = ta.z; tv[3] = ta.w;
    tv[4] = tb4.x; tv[5] = tb4.y; tv[6] = tb4.z; tv[7] = tb4.w;

    float c1 = pv[4], c2 = pv[9];
    float loss;
    if (tv[0] != 0.0f) {
        const float* tbx = tv + 1;
        float iou1 = iou_f(pv + 0, tbx);
        float iou2 = iou_f(pv + 5, tbx);
        float cl1 = coord_loss(pv + 0, tbx);
        float cl2 = coord_loss(pv + 5, tbx);
        int c = (int)tv[0] - 1;
        float cls = 0.0f;
        #pragma unroll
        for (int k = 0; k < 20; ++k) {
            float d = pv[10 + k] - (k == c ? 1.0f : 0.0f);
            cls += d * d;
        }
        float d1 = c1 - iou1, d2 = c2 - iou2;
        loss = d1 * d1 + d2 * d2 + L_COORD * (cl1 + cl2) + cls;
    } else {
        loss = L_NOOBJ * (c1 * c1 + c2 * c2);
    }
    float local = loss * INV_BATCH;

    // wave-64 reduce
    #pragma unroll
    for (int off = 32; off > 0; off >>= 1)
        local += __shfl_down(local, off);

    __shared__ float wsum[4];
    __shared__ int lastFlag;
    if (lane == 0) wsum[wid] = local;
    __syncthreads();

    if (tid == 0) {
        partial[blockIdx.x] = wsum[0] + wsum[1] + wsum[2] + wsum[3];
        __threadfence();                       // release
        unsigned int t = atomicAdd(counter, 1u);
        lastFlag = (t == NBLK - 1) ? 1 : 0;
    }
    __syncthreads();

    if (lastFlag) {
        __threadfence();                       // acquire
        float s = 0.0f;
        for (int i = tid; i < NBLK; i += 256)  // 3136/256 = 12.25 -> 13 iters max
            s += partial[i];
        #pragma unroll
        for (int off = 32; off > 0; off >>= 1)
            s += __shfl_down(s, off);
        __shared__ float fsum[4];
        if (lane == 0) fsum[wid] = s;
        __syncthreads();
        if (tid == 0)
            out[0] = fsum[0] + fsum[1] + fsum[2] + fsum[3];
    }
}

extern "C" void kernel_launch(void* const* d_in, const int* in_sizes, int n_in,
                              void* d_out, int out_size, void* d_ws, size_t ws_size,
                              hipStream_t stream) {
    const float* y_pre  = (const float*)d_in[0];
    const float* y_true = (const float*)d_in[1];
    float* out = (float*)d_out;
    float* partial = (float*)d_ws;                          // 3136 floats
    unsigned int* counter = (unsigned int*)((char*)d_ws + NBLK * sizeof(float));

    hipMemsetAsync(counter, 0, sizeof(unsigned int), stream);
    yolo_loss_kernel<<<NBLK, 256, 0, stream>>>(y_pre, y_true, partial, counter, out);
}

// Round 9
// 28.191 us; speedup vs baseline: 4.5794x; 4.5794x over previous
//
#include <hip/hip_runtime.h>

#define NCELLS (16384 * 7 * 7)   // 802816
#define NBLK (NCELLS / 256)      // 3136 blocks, 1 cell/thread
#define NPART (NBLK * 4)         // one partial per wave = 12544
#define INV_BATCH (1.0f / 16384.0f)
#define EPS 1e-12f
#define IMG 448.0f
#define CELL (448.0f / 7.0f)     // 64
#define L_COORD 5.0f
#define L_NOOBJ 0.5f

__device__ __forceinline__ float iou_f(const float* bp, const float* bt) {
    float cxp = bp[0] * CELL, cyp = bp[1] * CELL;
    float wp  = bp[2] * IMG,  hp  = bp[3] * IMG;
    float cxt = bt[0] * CELL, cyt = bt[1] * CELL;
    float wt  = bt[2] * IMG,  ht  = bt[3] * IMG;
    float iw = fmaxf(fminf(cxp + wp * 0.5f, cxt + wt * 0.5f) -
                     fmaxf(cxp - wp * 0.5f, cxt - wt * 0.5f), 0.0f);
    float ih = fmaxf(fminf(cyp + hp * 0.5f, cyt + ht * 0.5f) -
                     fmaxf(cyp - hp * 0.5f, cyt - ht * 0.5f), 0.0f);
    float inter = iw * ih;
    float uni = wp * hp + wt * ht - inter;
    return inter / (uni + EPS);
}

__device__ __forceinline__ float coord_loss(const float* bp, const float* tb) {
    float xy = (bp[0] - tb[0]) * (bp[0] - tb[0]) + (bp[1] - tb[1]) * (bp[1] - tb[1]);
    float s2 = sqrtf(bp[2] + EPS) - sqrtf(tb[2] + EPS);
    float s3 = sqrtf(bp[3] + EPS) - sqrtf(tb[3] + EPS);
    return xy + s2 * s2 + s3 * s3;
}

// Kernel 1: 1 cell/thread, direct loads, wave-64 shfl reduce,
// ONE partial per wave (lane-0 plain store). No LDS, no barriers.
__global__ void __launch_bounds__(256) yolo_partial_kernel(
        const float* __restrict__ y_pre,
        const float* __restrict__ y_true,
        float* __restrict__ partial) {
    const int tid = threadIdx.x;
    const int idx = blockIdx.x * 256 + tid;

    float pv[30];
    const float2* p2 = reinterpret_cast<const float2*>(y_pre + (size_t)idx * 30);
    #pragma unroll
    for (int i = 0; i < 15; ++i) {
        float2 v = p2[i];
        pv[2 * i]     = v.x;
        pv[2 * i + 1] = v.y;
    }
    float tv[8];
    const float4* t4 = reinterpret_cast<const float4*>(y_true) + (size_t)idx * 2;
    float4 ta = t4[0], tb4 = t4[1];
    tv[0] = ta.x; tv[1] = ta.y; tv[2] = ta.z; tv[3] = ta.w;
    tv[4] = tb4.x; tv[5] = tb4.y; tv[6] = tb4.z; tv[7] = tb4.w;

    float c1 = pv[4], c2 = pv[9];
    float loss;
    if (tv[0] != 0.0f) {
        const float* tbx = tv + 1;
        float iou1 = iou_f(pv + 0, tbx);
        float iou2 = iou_f(pv + 5, tbx);
        float cl1 = coord_loss(pv + 0, tbx);
        float cl2 = coord_loss(pv + 5, tbx);
        int c = (int)tv[0] - 1;
        float cls = 0.0f;
        #pragma unroll
        for (int k = 0; k < 20; ++k) {
            float d = pv[10 + k] - (k == c ? 1.0f : 0.0f);
            cls += d * d;
        }
        float d1 = c1 - iou1, d2 = c2 - iou2;
        loss = d1 * d1 + d2 * d2 + L_COORD * (cl1 + cl2) + cls;
    } else {
        loss = L_NOOBJ * (c1 * c1 + c2 * c2);
    }
    float local = loss * INV_BATCH;

    #pragma unroll
    for (int off = 32; off > 0; off >>= 1)
        local += __shfl_down(local, off);

    if ((tid & 63) == 0)
        partial[blockIdx.x * 4 + (tid >> 6)] = local;   // per-wave, no barrier
}

// Kernel 2: one block sums 12544 partials (float4 loads), writes out[0].
__global__ void __launch_bounds__(256) yolo_final_kernel(
        const float* __restrict__ partial,
        float* __restrict__ out) {
    const int tid = threadIdx.x;
    const float4* p4 = reinterpret_cast<const float4*>(partial);
    float local = 0.0f;
    #pragma unroll 4
    for (int i = tid; i < NPART / 4; i += 256) {        // 3136 float4 -> 13 iters
        float4 v = p4[i];
        local += (v.x + v.y) + (v.z + v.w);
    }
    #pragma unroll
    for (int off = 32; off > 0; off >>= 1)
        local += __shfl_down(local, off);

    __shared__ float wsum[4];
    if ((tid & 63) == 0) wsum[tid >> 6] = local;
    __syncthreads();
    if (tid == 0)
        out[0] = wsum[0] + wsum[1] + wsum[2] + wsum[3];
}

extern "C" void kernel_launch(void* const* d_in, const int* in_sizes, int n_in,
                              void* d_out, int out_size, void* d_ws, size_t ws_size,
                              hipStream_t stream) {
    const float* y_pre  = (const float*)d_in[0];
    const float* y_true = (const float*)d_in[1];
    float* out = (float*)d_out;
    float* partial = (float*)d_ws;   // 12544 floats = 49 KB

    yolo_partial_kernel<<<NBLK, 256, 0, stream>>>(y_pre, y_true, partial);
    yolo_final_kernel<<<1, 256, 0, stream>>>(partial, out);
}